// Round 7
// baseline (602.530 us; speedup 1.0000x reference)
//
#include <hip/hip_runtime.h>
#include <hip/hip_bf16.h>

#define BATCH   16384
#define IN_F    1024
#define OUT_F   1024
#define KCOLS   11
#define KPL     12          // 11 basis planes + 1 x-plane (for W)
#define KP      (KPL*IN_F)  // 12288
#define KHALF   (KP/2)      // 6144 per split-K block
#define NTKH    (KHALF/64)  // 96 K-tiles of 64 per half
#define NITH    (NTKH/2)    // 48 main-loop iterations (2 K-tiles each)
#define LN_EPS  1e-5f

typedef __attribute__((ext_vector_type(8))) short short8;
typedef __attribute__((ext_vector_type(4))) float f32x4;

static __device__ __forceinline__ unsigned short f2bf(float f) {
  __hip_bfloat16 h = __float2bfloat16(f);
  return *reinterpret_cast<unsigned short*>(&h);
}

// Cox-de Boor, faithful to the reference's in-place variant.
// All denominators are compile-time constants -> multiply by folded reciprocal.
__device__ __forceinline__ void bspline_basis(float x, float bas[KCOLS]) {
  const float s = 1.0f / 11.0f;
  float kn[12];
#pragma unroll
  for (int j = 0; j < 12; ++j) kn[j] = (float)j * s;
  kn[11] = 1.0f;
#pragma unroll
  for (int j = 0; j < 11; ++j)
    bas[j] = (x >= kn[j] && x < kn[j + 1]) ? 1.0f : 0.0f;
#pragma unroll
  for (int d = 1; d <= 3; ++d) {
#pragma unroll
    for (int j = 0; j < 11 - d; ++j) {
      const float r1 = 1.0f / (kn[j + d] - kn[j]);
      const float r2 = 1.0f / (kn[j + d + 1] - kn[j + 1]);
      float a = (x - kn[j]) * r1;
      float c = (kn[j + d + 1] - x) * r2;
      bas[j] = a * bas[j] + c * bas[j + 1];
    }
  }
}

// A[localRow][k*1024 + i] (bf16): 11 basis planes + x plane.
__global__ __launch_bounds__(256) void featgen(const float* __restrict__ X,
                                               unsigned short* __restrict__ A,
                                               int row0) {
  const int brow = blockIdx.x;
  const int i0 = threadIdx.x * 4;
  const float4 xv = *reinterpret_cast<const float4*>(X + (size_t)(row0 + brow) * IN_F + i0);
  float xs[4] = {xv.x, xv.y, xv.z, xv.w};
  float bas[4][KCOLS];
#pragma unroll
  for (int t = 0; t < 4; ++t) bspline_basis(xs[t], bas[t]);
  unsigned short* outp = A + (size_t)brow * KP + i0;
#pragma unroll
  for (int k = 0; k < KCOLS; ++k) {
    ushort4 u;
    u.x = f2bf(bas[0][k]); u.y = f2bf(bas[1][k]);
    u.z = f2bf(bas[2][k]); u.w = f2bf(bas[3][k]);
    *reinterpret_cast<ushort4*>(outp + (size_t)k * IN_F) = u;
  }
  ushort4 u;
  u.x = f2bf(xs[0]); u.y = f2bf(xs[1]); u.z = f2bf(xs[2]); u.w = f2bf(xs[3]);
  *reinterpret_cast<ushort4*>(outp + (size_t)KCOLS * IN_F) = u;
}

// ---- bgen2: pack B (cp planes + W plane) directly in MFMA-fragment order.
// Element (o, k): o = bn*256 + ob*16 + fr, k = tg*64 + kk*32 + g4*8 + e,
// value = (k/1024 < 11) ? cp[o][k%1024][k/1024] : W[o][k%1024].
// BP short-index = ((tg*4+bn)*16+ob)*2*512 ... = tg*65536 + bn*16384 +
//                  ob*1024 + kk*512 + (g4*16+fr)*8 + e.
// A wave's fragment load is then BP + base + lane*8 : one coalesced b128.
__global__ __launch_bounds__(256) void bgen2(const float* __restrict__ CP,
                                             const float* __restrict__ W,
                                             unsigned short* __restrict__ BP) {
  const int bx = blockIdx.x;            // 4 bn x 16 ob x 96 tgg
  const int bn = bx / (16 * 96);
  const int rem = bx % (16 * 96);
  const int ob = rem / 96;
  const int tgg = rem % 96;
  const int tid = threadIdx.x;
  const int lane = tid & 63;
  const int kk = (tid >> 6) & 1;
  const int ts = tid >> 7;
  const int tg = tgg * 2 + ts;
  const int fr = lane & 15;
  const int g4 = lane >> 4;
  const int o = bn * 256 + ob * 16 + fr;
  const int k0 = tg * 64 + kk * 32 + g4 * 8;
  const int p = k0 >> 10;               // plane (same for all 8 elems)
  const int i0 = k0 & 1023;
  unsigned short v[8];
#pragma unroll
  for (int e = 0; e < 8; ++e) {
    float f = (p < KCOLS) ? CP[((size_t)o * IN_F + i0 + e) * KCOLS + p]
                          : W[(size_t)o * IN_F + i0 + e];
    v[e] = f2bf(f);
  }
  unsigned short* dst = BP + (size_t)tg * 65536 + bn * 16384 + ob * 1024 + kk * 512 + lane * 8;
  *reinterpret_cast<short8*>(dst) = *reinterpret_cast<short8*>(v);
}

// -------- 256x256 single-barrier split-K GEMM; A via LDS, B via registers ----
// ks=0 blocks -> Cc, ks=1 blocks -> Cp. Grid = nbm*8; 8192 rows -> 256 WGs.
// 512 thr = 8 waves (2M x 4N); BK=64; LDS 64 KiB = 2 x A-tile[256x64].
// B fragments loaded straight from packed global (L2-resident) one phase ahead.
// One trailing barrier per phase; WAITV(5) at P4/P8 (5 vmem ops issued after
// the awaited A-tile's last stage: 4 B-loads + 1 stage).

#define BAR()    __builtin_amdgcn_s_barrier()
#define SCHED0() __builtin_amdgcn_sched_barrier(0)
#define WAITV(N) asm volatile("s_waitcnt vmcnt(" #N ")" ::: "memory")

__global__ __launch_bounds__(512, 2) void gemm8p(const unsigned short* __restrict__ A,
                                                 const unsigned short* __restrict__ BP,
                                                 float* __restrict__ Cc,
                                                 float* __restrict__ Cp, int nbm) {
  __shared__ unsigned short lds[2][256 * 64];   // 2 x 32 KiB, A only
  const int tid  = (int)threadIdx.x;
  const int lane = tid & 63;
  const int w    = tid >> 6;
  const int wm   = w >> 2;       // 0..1
  const int wn   = w & 3;        // 0..3

  // XCD-aware bijective swizzle; per-XCD chunk = {4 bm} x {2 ks} x {4 bn}.
  const int nwg = nbm * 8;
  const int cpx = nwg >> 3;
  const int bid = (int)blockIdx.x;
  const int swz = (bid & 7) * cpx + (bid >> 3);
  const int bn = swz & 3;
  const int ks = (swz >> 2) & 1;
  const int bm = swz >> 3;
  const size_t koff = (size_t)ks * KHALF;
  float* __restrict__ C = ks ? Cp : Cc;

  // A staging: one issue = 512 thr x 16 B = 64 rows x 64 cols; 4 issues/tile.
  // Linear LDS dest; source col carries the inverse swizzle c ^ (row&7).
  const int srow = (w << 3) + (lane >> 3);            // 0..63 within one issue
  const int scol = ((lane & 7) ^ (lane >> 3)) << 3;   // element col, swizzled
  const unsigned short* aB = A + (size_t)(bm * 256 + srow) * KP + koff + scol;

#define STAGE_A(T, ISS, BUF)                                                          \
  do {                                                                                \
    if ((T) < NTKH) {                                                                 \
      const unsigned short* g_ = aB + (size_t)(ISS) * 64 * KP + (size_t)(T) * 64;     \
      __builtin_amdgcn_global_load_lds((const __attribute__((address_space(1))) void*)g_, \
          (__attribute__((address_space(3))) void*)(&lds[BUF][(ISS) * 4096 + w * 512]), 16, 0, 0); \
    }                                                                                 \
  } while (0)

  // A fragment reads (ds_read_b128, swizzled col)
  const int fr = lane & 15;
  const int g4 = lane >> 4;
  const int s7 = lane & 7;
  const int col0 = ((g4 ^ s7) << 3);        // kk=0 (elements)
  const int col1 = (((4 + g4) ^ s7) << 3);  // kk=1

  // B fragment loads: packed global, one b128 per (n_, kk_).
  const unsigned short* bpT = BP + (size_t)(ks * NTKH) * 65536 +
                              (size_t)bn * 16384 + (size_t)wn * 4096 + (size_t)lane * 8;

#define LOADB_G(DST, NB, TG)                                                   \
  do {                                                                         \
    const unsigned short* q_ = bpT + (size_t)(TG) * 65536;                     \
    _Pragma("unroll") for (int n_ = 0; n_ < 2; ++n_)                           \
    _Pragma("unroll") for (int kk_ = 0; kk_ < 2; ++kk_)                        \
      DST[n_][kk_] = *reinterpret_cast<const short8*>(q_ + ((NB) + n_) * 1024 + kk_ * 512); \
  } while (0)

  short8 aF[4][2], bF0[2][2], bF1[2][2];
  f32x4 acc[8][4] = {};

#define LOADA(MB, BUF)                                                         \
  do {                                                                         \
    _Pragma("unroll") for (int m_ = 0; m_ < 4; ++m_) {                         \
      const unsigned short* p_ = &lds[BUF][(wm * 128 + ((MB) + m_) * 16 + fr) * 64]; \
      aF[m_][0] = *reinterpret_cast<const short8*>(p_ + col0);                 \
      aF[m_][1] = *reinterpret_cast<const short8*>(p_ + col1);                 \
    }                                                                          \
  } while (0)

#define MFMAQ(MB, NB, BF)                                                      \
  do {                                                                         \
    __builtin_amdgcn_s_setprio(1);                                             \
    _Pragma("unroll") for (int m_ = 0; m_ < 4; ++m_)                           \
    _Pragma("unroll") for (int n_ = 0; n_ < 2; ++n_)                           \
    _Pragma("unroll") for (int kk_ = 0; kk_ < 2; ++kk_)                        \
      acc[(MB) + m_][(NB) + n_] = __builtin_amdgcn_mfma_f32_16x16x32_bf16(     \
          aF[m_][kk_], BF[n_][kk_], acc[(MB) + m_][(NB) + n_], 0, 0, 0);       \
    __builtin_amdgcn_s_setprio(0);                                             \
  } while (0)

  // prologue: tile0 -> buf0 (4 issues), tile1 iss0 -> buf1, bF0(tile0).
  STAGE_A(0, 0, 0); STAGE_A(0, 1, 0); STAGE_A(0, 2, 0); STAGE_A(0, 3, 0);
  STAGE_A(1, 0, 1);
  LOADB_G(bF0, 0, 0);
  WAITV(5);
  BAR();

#pragma unroll 1
  for (int j = 0; j < NITH; ++j) {
    const int ta = 2 * j, tb = 2 * j + 1;
    const int tgn = (2 * j + 2 < NTKH) ? 2 * j + 2 : NTKH - 1;  // next iter's a
    // P1: quad(m0-3,n0-1) tile a (buf0); load bF1(a); stage tb iss1 -> buf1
    LOADA(0, 0);
    LOADB_G(bF1, 2, ta);
    STAGE_A(tb, 1, 1);
    MFMAQ(0, 0, bF0);
    SCHED0(); BAR();
    // P2: quad(m0-3,n2-3) (reuses aF); stage tb iss2
    STAGE_A(tb, 2, 1);
    MFMAQ(0, 2, bF1);
    SCHED0(); BAR();
    // P3: quad(m4-7,n0-1); stage tb iss3
    LOADA(4, 0);
    STAGE_A(tb, 3, 1);
    MFMAQ(4, 0, bF0);
    SCHED0(); BAR();
    // P4: quad(m4-7,n2-3); load bF0(b); stage ta+2 iss0 -> buf0
    //     (buf0 A-reads finished @P3; barrier P3 makes the overwrite safe)
    LOADB_G(bF0, 0, tb);
    STAGE_A(ta + 2, 0, 0);
    MFMAQ(4, 2, bF1);
    if (j < NITH - 1) { WAITV(5); } else { WAITV(0); }   // tb fully staged
    SCHED0(); BAR();
    // P5: tile b (buf1) quad(m0-3,n0-1); load bF1(b); stage ta+2 iss1
    LOADA(0, 1);
    LOADB_G(bF1, 2, tb);
    STAGE_A(ta + 2, 1, 0);
    MFMAQ(0, 0, bF0);
    SCHED0(); BAR();
    // P6: quad(m0-3,n2-3); stage ta+2 iss2
    STAGE_A(ta + 2, 2, 0);
    MFMAQ(0, 2, bF1);
    SCHED0(); BAR();
    // P7: quad(m4-7,n0-1); stage ta+2 iss3
    LOADA(4, 1);
    STAGE_A(ta + 2, 3, 0);
    MFMAQ(4, 0, bF0);
    SCHED0(); BAR();
    // P8: quad(m4-7,n2-3); load bF0(next a); stage ta+3 iss0 -> buf1
    LOADB_G(bF0, 0, tgn);
    STAGE_A(ta + 3, 0, 1);
    MFMAQ(4, 2, bF1);
    if (j < NITH - 1) { WAITV(5); }                      // ta+2 fully staged
    SCHED0(); BAR();
  }

  // C/D layout (verified m89/m91): col = lane&15, row = (lane>>4)*4 + reg
  const size_t r0 = (size_t)bm * 256 + wm * 128 + (lane >> 4) * 4;
  const int c0 = bn * 256 + wn * 64 + fr;
#pragma unroll
  for (int m = 0; m < 8; ++m)
#pragma unroll
    for (int n = 0; n < 4; ++n)
#pragma unroll
      for (int r = 0; r < 4; ++r)
        C[(r0 + m * 16 + r) * OUT_F + (c0 + n * 16)] = acc[m][n][r];
}

// Row LayerNorm over C0+C1+bias, written in place to C0.
__global__ __launch_bounds__(256) void ln_kernel(float* __restrict__ C,
                                                 const float* __restrict__ P,
                                                 const float* __restrict__ bias,
                                                 const float* __restrict__ gamma,
                                                 const float* __restrict__ beta) {
  const int row = blockIdx.x;
  const int tid = threadIdx.x;
  float4 v = *reinterpret_cast<const float4*>(C + (size_t)row * OUT_F + tid * 4);
  const float4 p = *reinterpret_cast<const float4*>(P + (size_t)row * OUT_F + tid * 4);
  const float4 bb = *reinterpret_cast<const float4*>(bias + tid * 4);
  v.x += p.x + bb.x; v.y += p.y + bb.y; v.z += p.z + bb.z; v.w += p.w + bb.w;
  float s = v.x + v.y + v.z + v.w;
  float q = v.x * v.x + v.y * v.y + v.z * v.z + v.w * v.w;
#pragma unroll
  for (int off = 32; off > 0; off >>= 1) {
    s += __shfl_down(s, off);
    q += __shfl_down(q, off);
  }
  __shared__ float red[8];
  const int wave = tid >> 6, lane = tid & 63;
  if (lane == 0) { red[wave] = s; red[4 + wave] = q; }
  __syncthreads();
  s = red[0] + red[1] + red[2] + red[3];
  q = red[4] + red[5] + red[6] + red[7];
  const float mu = s * (1.0f / OUT_F);
  const float var = q * (1.0f / OUT_F) - mu * mu;
  const float rs = rsqrtf(var + LN_EPS);
  const float4 g = *reinterpret_cast<const float4*>(gamma + tid * 4);
  const float4 be = *reinterpret_cast<const float4*>(beta + tid * 4);
  float4 o;
  o.x = g.x * (v.x - mu) * rs + be.x;
  o.y = g.y * (v.y - mu) * rs + be.y;
  o.z = g.z * (v.z - mu) * rs + be.z;
  o.w = g.w * (v.w - mu) * rs + be.w;
  *reinterpret_cast<float4*>(C + (size_t)row * OUT_F + tid * 4) = o;
}

extern "C" void kernel_launch(void* const* d_in, const int* in_sizes, int n_in,
                              void* d_out, int out_size, void* d_ws, size_t ws_size,
                              hipStream_t stream) {
  const float* x     = (const float*)d_in[0];
  const float* cp    = (const float*)d_in[1];
  const float* W     = (const float*)d_in[2];
  const float* bias  = (const float*)d_in[3];
  const float* gamma = (const float*)d_in[4];
  const float* beta  = (const float*)d_in[5];
  float* out = (float*)d_out;

  unsigned short* BP = (unsigned short*)d_ws;
  const size_t bBytes = (size_t)OUT_F * KP * sizeof(unsigned short);   // 24 MiB packed
  size_t avail = ws_size > bBytes ? ws_size - bBytes : 0;
  // per-row: 24 KiB bf16 features + 4 KiB fp32 partial
  const size_t perRow = (size_t)KP * 2 + (size_t)OUT_F * 4;
  long long fit = (long long)(avail / perRow);
  int chunk;
  if (fit >= BATCH)     chunk = BATCH;   // 512 WGs = 2 full fill rounds
  else if (fit >= 8192) chunk = 8192;    // 256 WGs = exact full fill
  else                  chunk = (int)((fit / 256) * 256);
  if (chunk < 256) chunk = 256;

  unsigned short* Af = (unsigned short*)((char*)d_ws + bBytes);
  float* P = (float*)(Af + (size_t)chunk * KP);

  bgen2<<<4 * 16 * 96, 256, 0, stream>>>(cp, W, BP);
  for (int r0 = 0; r0 < BATCH; r0 += chunk) {
    const int rows = (BATCH - r0 < chunk) ? (BATCH - r0) : chunk;
    featgen<<<rows, 256, 0, stream>>>(x, Af, r0);
    const int nbm = rows / 256;
    gemm8p<<<nbm * 8, 512, 0, stream>>>(Af, BP, out + (size_t)r0 * OUT_F, P, nbm);
    ln_kernel<<<rows, 256, 0, stream>>>(out + (size_t)r0 * OUT_F, P, bias, gamma, beta);
  }
}

// Round 8
// 476.905 us; speedup vs baseline: 1.2634x; 1.2634x over previous
//
#include <hip/hip_runtime.h>
#include <hip/hip_bf16.h>

#define BATCH   16384
#define IN_F    1024
#define OUT_F   1024
#define KCOLS   11
#define KPL     12          // 11 basis planes + 1 x-plane (for W)
#define KP      (KPL*IN_F)  // 12288
#define KHALF   (KP/2)      // 6144 per split-K block
#define NTKH    (KHALF/64)  // 96 K-tiles of 64 per half
#define NITH    (NTKH/2)    // 48 main-loop iterations (2 K-tiles each)
#define LN_EPS  1e-5f

typedef __attribute__((ext_vector_type(8))) short short8;
typedef __attribute__((ext_vector_type(4))) float f32x4;

static __device__ __forceinline__ unsigned short f2bf(float f) {
  __hip_bfloat16 h = __float2bfloat16(f);
  return *reinterpret_cast<unsigned short*>(&h);
}

// Cox-de Boor, faithful to the reference's in-place variant.
// All denominators are compile-time constants -> multiply by folded reciprocal.
__device__ __forceinline__ void bspline_basis(float x, float bas[KCOLS]) {
  const float s = 1.0f / 11.0f;
  float kn[12];
#pragma unroll
  for (int j = 0; j < 12; ++j) kn[j] = (float)j * s;
  kn[11] = 1.0f;
#pragma unroll
  for (int j = 0; j < 11; ++j)
    bas[j] = (x >= kn[j] && x < kn[j + 1]) ? 1.0f : 0.0f;
#pragma unroll
  for (int d = 1; d <= 3; ++d) {
#pragma unroll
    for (int j = 0; j < 11 - d; ++j) {
      const float r1 = 1.0f / (kn[j + d] - kn[j]);
      const float r2 = 1.0f / (kn[j + d + 1] - kn[j + 1]);
      float a = (x - kn[j]) * r1;
      float c = (kn[j + d + 1] - x) * r2;
      bas[j] = a * bas[j] + c * bas[j + 1];
    }
  }
}

// A[localRow][k*1024 + i] (bf16): 11 basis planes + x plane.
__global__ __launch_bounds__(256) void featgen(const float* __restrict__ X,
                                               unsigned short* __restrict__ A,
                                               int row0) {
  const int brow = blockIdx.x;
  const int i0 = threadIdx.x * 4;
  const float4 xv = *reinterpret_cast<const float4*>(X + (size_t)(row0 + brow) * IN_F + i0);
  float xs[4] = {xv.x, xv.y, xv.z, xv.w};
  float bas[4][KCOLS];
#pragma unroll
  for (int t = 0; t < 4; ++t) bspline_basis(xs[t], bas[t]);
  unsigned short* outp = A + (size_t)brow * KP + i0;
#pragma unroll
  for (int k = 0; k < KCOLS; ++k) {
    ushort4 u;
    u.x = f2bf(bas[0][k]); u.y = f2bf(bas[1][k]);
    u.z = f2bf(bas[2][k]); u.w = f2bf(bas[3][k]);
    *reinterpret_cast<ushort4*>(outp + (size_t)k * IN_F) = u;
  }
  ushort4 u;
  u.x = f2bf(xs[0]); u.y = f2bf(xs[1]); u.z = f2bf(xs[2]); u.w = f2bf(xs[3]);
  *reinterpret_cast<ushort4*>(outp + (size_t)KCOLS * IN_F) = u;
}

// Bmat[o][k*1024 + i] (bf16): cp planes + W plane.
__global__ __launch_bounds__(256) void bgen(const float* __restrict__ CP,
                                            const float* __restrict__ W,
                                            unsigned short* __restrict__ Bm) {
  const int o = blockIdx.x;
  const int i0 = threadIdx.x * 4;
  unsigned short* outp = Bm + (size_t)o * KP + i0;
#pragma unroll
  for (int k = 0; k < KCOLS; ++k) {
    ushort4 u;
    u.x = f2bf(CP[((size_t)o * IN_F + i0 + 0) * KCOLS + k]);
    u.y = f2bf(CP[((size_t)o * IN_F + i0 + 1) * KCOLS + k]);
    u.z = f2bf(CP[((size_t)o * IN_F + i0 + 2) * KCOLS + k]);
    u.w = f2bf(CP[((size_t)o * IN_F + i0 + 3) * KCOLS + k]);
    *reinterpret_cast<ushort4*>(outp + (size_t)k * IN_F) = u;
  }
  ushort4 u;
  u.x = f2bf(W[(size_t)o * IN_F + i0 + 0]);
  u.y = f2bf(W[(size_t)o * IN_F + i0 + 1]);
  u.z = f2bf(W[(size_t)o * IN_F + i0 + 2]);
  u.w = f2bf(W[(size_t)o * IN_F + i0 + 3]);
  *reinterpret_cast<ushort4*>(outp + (size_t)KCOLS * IN_F) = u;
}

// ---- 256x256 single-barrier split-K GEMM, fragment reads pipelined 1 phase --
// ks=0 blocks -> Cc, ks=1 blocks -> Cp. Grid = nbm*8; 8192 rows -> 256 WGs.
// 512 thr = 8 waves (2M x 4N); BK=64; LDS 128 KiB double-buffered (A+B).
// Each phase: issue NEXT quad's ds_reads, stage, run CURRENT quad's MFMA on
// fragments read last phase (lgkm wait ~free), one trailing barrier.
// Counted waits: buf1's last stage @P2 -> WAITV(2) @P3; buf0's @P6 -> WAITV(2) @P7.

#define BAR()    __builtin_amdgcn_s_barrier()
#define SCHED0() __builtin_amdgcn_sched_barrier(0)
#define WAITV(N) asm volatile("s_waitcnt vmcnt(" #N ")" ::: "memory")

__global__ __launch_bounds__(512, 2) void gemm8p(const unsigned short* __restrict__ A,
                                                 const unsigned short* __restrict__ Bm,
                                                 float* __restrict__ Cc,
                                                 float* __restrict__ Cp, int nbm) {
  __shared__ unsigned short lds[2][2][2][128 * 64];  // [buf][A=0/B=1][half][...]
  const int tid  = (int)threadIdx.x;
  const int lane = tid & 63;
  const int w    = tid >> 6;
  const int wm   = w >> 2;       // 0..1
  const int wn   = w & 3;        // 0..3

  // XCD-aware bijective swizzle; per-XCD chunk = {4 bm} x {2 ks} x {4 bn}.
  const int nwg = nbm * 8;
  const int cpx = nwg >> 3;
  const int bid = (int)blockIdx.x;
  const int swz = (bid & 7) * cpx + (bid >> 3);
  const int bn = swz & 3;
  const int ks = (swz >> 2) & 1;
  const int bm = swz >> 3;
  const size_t koff = (size_t)ks * KHALF;
  float* __restrict__ C = ks ? Cp : Cc;

  // staging: one issue = 512 thr x 16 B = 64 rows x 64 cols.
  // Linear LDS dest; source col carries the inverse swizzle c ^ (row&7).
  const int srow = (w << 3) + (lane >> 3);            // 0..63 within one issue
  const int scol = ((lane & 7) ^ (lane >> 3)) << 3;   // element col, swizzled
  const unsigned short* aB = A  + (size_t)(bm * 256 + srow) * KP + koff + scol;
  const unsigned short* bB = Bm + (size_t)(bn * 256 + srow) * KP + koff + scol;

#define STAGE(T, AB, H, BUF)                                                          \
  do {                                                                                \
    if ((T) < NTKH) {                                                                 \
      const unsigned short* g_ = ((AB) ? bB : aB) + (size_t)(H) * 128 * KP + (size_t)(T) * 64; \
      unsigned short* l_ = &lds[BUF][AB][H][w * 512];                                 \
      __builtin_amdgcn_global_load_lds((const __attribute__((address_space(1))) void*)g_,       \
                                       (__attribute__((address_space(3))) void*)l_, 16, 0, 0);  \
      __builtin_amdgcn_global_load_lds((const __attribute__((address_space(1))) void*)(g_ + (size_t)64 * KP), \
                                       (__attribute__((address_space(3))) void*)(l_ + 4096), 16, 0, 0); \
    }                                                                                 \
  } while (0)

  // fragment reads (ds_read_b128, swizzled col)
  const int fr = lane & 15;
  const int g4 = lane >> 4;
  const int s7 = lane & 7;
  const int col0 = ((g4 ^ s7) << 3);        // kk=0 (elements)
  const int col1 = (((4 + g4) ^ s7) << 3);  // kk=1
  const unsigned short* aH[2] = {&lds[0][0][wm][0], &lds[1][0][wm][0]};
  const unsigned short* bH[2] = {&lds[0][1][wn >> 1][0], &lds[1][1][wn >> 1][0]};
  const int brow0 = (wn & 1) * 64;

  short8 aFA[4][2], aFB[4][2], bF0[2][2], bF1[2][2];
  f32x4 acc[8][4] = {};

#define LOADA_D(DST, MB, BUF)                                                  \
  do {                                                                         \
    _Pragma("unroll") for (int m_ = 0; m_ < 4; ++m_) {                         \
      const unsigned short* p_ = aH[BUF] + ((MB) + m_) * 1024 + fr * 64;       \
      DST[m_][0] = *reinterpret_cast<const short8*>(p_ + col0);                \
      DST[m_][1] = *reinterpret_cast<const short8*>(p_ + col1);                \
    }                                                                          \
  } while (0)

#define LOADB(DST, NB, BUF)                                                    \
  do {                                                                         \
    _Pragma("unroll") for (int n_ = 0; n_ < 2; ++n_) {                         \
      const unsigned short* p_ = bH[BUF] + (brow0 + ((NB) + n_) * 16 + fr) * 64; \
      DST[n_][0] = *reinterpret_cast<const short8*>(p_ + col0);                \
      DST[n_][1] = *reinterpret_cast<const short8*>(p_ + col1);                \
    }                                                                          \
  } while (0)

#define MFMAQ_D(AFR, MB, NB, BF)                                               \
  do {                                                                         \
    __builtin_amdgcn_s_setprio(1);                                             \
    _Pragma("unroll") for (int m_ = 0; m_ < 4; ++m_)                           \
    _Pragma("unroll") for (int n_ = 0; n_ < 2; ++n_)                           \
    _Pragma("unroll") for (int kk_ = 0; kk_ < 2; ++kk_)                        \
      acc[(MB) + m_][(NB) + n_] = __builtin_amdgcn_mfma_f32_16x16x32_bf16(     \
          AFR[m_][kk_], BF[n_][kk_], acc[(MB) + m_][(NB) + n_], 0, 0, 0);      \
    __builtin_amdgcn_s_setprio(0);                                             \
  } while (0)

  // prologue: tile0 A+B -> buf0 (8 issues); tile1 B -> buf1 (4 issues);
  // wait buf0 complete (leave buf1-B's 4 in flight); prefetch Q1 fragments.
  STAGE(0, 0, 0, 0); STAGE(0, 0, 1, 0);
  STAGE(0, 1, 0, 0); STAGE(0, 1, 1, 0);
  STAGE(1, 1, 0, 1); STAGE(1, 1, 1, 1);
  WAITV(4);
  BAR();
  LOADA_D(aFA, 0, 0);
  LOADB(bF0, 0, 0);

#pragma unroll 1
  for (int j = 0; j < NITH; ++j) {
    const int tb = 2 * j + 1, t2 = 2 * j + 2, t3 = 2 * j + 3;
    // P1: MFMA Q1(m0-3,n0-1,buf0) on aFA/bF0 (read last phase);
    //     prefetch bF1(buf0); stage tb:A:h0 -> buf1
    LOADB(bF1, 2, 0);
    STAGE(tb, 0, 0, 1);
    MFMAQ_D(aFA, 0, 0, bF0);
    SCHED0(); BAR();
    // P2: Q2(m0-3,n2-3) aFA/bF1; prefetch aFB=A(m4-7,buf0); stage tb:A:h1 -> buf1
    LOADA_D(aFB, 4, 0);
    STAGE(tb, 0, 1, 1);
    MFMAQ_D(aFA, 0, 2, bF1);
    SCHED0(); BAR();
    // P3: Q3(m4-7,n0-1) aFB/bF0; stage t2:B:h0 -> buf0 (B-buf0 reads issued @P1,
    //     lgkm-drained @P2's MFMA); counted wait: buf1 (A @P1/P2 + B @prev P7/P8) ready
    STAGE(t2, 1, 0, 0);
    MFMAQ_D(aFB, 4, 0, bF0);
    if (j < NITH - 1) { WAITV(2); } else { WAITV(0); }
    SCHED0(); BAR();
    // P4: Q4(m4-7,n2-3) aFB/bF1; prefetch aFA=A(m0-3,buf1), bF0(buf1); stage t2:B:h1 -> buf0
    LOADA_D(aFA, 0, 1);
    LOADB(bF0, 0, 1);
    STAGE(t2, 1, 1, 0);
    MFMAQ_D(aFB, 4, 2, bF1);
    SCHED0(); BAR();
    // P5: Q5(m0-3,n0-1,buf1) aFA/bF0; prefetch bF1(buf1); stage t2:A:h0 -> buf0
    LOADB(bF1, 2, 1);
    STAGE(t2, 0, 0, 0);
    MFMAQ_D(aFA, 0, 0, bF0);
    SCHED0(); BAR();
    // P6: Q6(m0-3,n2-3) aFA/bF1; prefetch aFB=A(m4-7,buf1); stage t2:A:h1 -> buf0
    LOADA_D(aFB, 4, 1);
    STAGE(t2, 0, 1, 0);
    MFMAQ_D(aFA, 0, 2, bF1);
    SCHED0(); BAR();
    // P7: Q7(m4-7,n0-1) aFB/bF0; stage t3:B:h0 -> buf1 (B-buf1 reads drained @P6);
    //     counted wait: buf0 (t2 staged P3..P6) ready
    STAGE(t3, 1, 0, 1);
    MFMAQ_D(aFB, 4, 0, bF0);
    if (j < NITH - 1) { WAITV(2); } else { WAITV(0); }
    SCHED0(); BAR();
    // P8: Q8(m4-7,n2-3) aFB/bF1; prefetch next Q1: aFA=A(m0-3,buf0), bF0(buf0);
    //     stage t3:B:h1 -> buf1
    LOADA_D(aFA, 0, 0);
    LOADB(bF0, 0, 0);
    STAGE(t3, 1, 1, 1);
    MFMAQ_D(aFB, 4, 2, bF1);
    SCHED0(); BAR();
  }

  // C/D layout (verified m89/m91): col = lane&15, row = (lane>>4)*4 + reg
  const size_t r0 = (size_t)bm * 256 + wm * 128 + (lane >> 4) * 4;
  const int c0 = bn * 256 + wn * 64 + fr;
#pragma unroll
  for (int m = 0; m < 8; ++m)
#pragma unroll
    for (int n = 0; n < 4; ++n)
#pragma unroll
      for (int r = 0; r < 4; ++r)
        C[(r0 + m * 16 + r) * OUT_F + (c0 + n * 16)] = acc[m][n][r];
}

// Row LayerNorm over C0+C1+bias, written in place to C0.
__global__ __launch_bounds__(256) void ln_kernel(float* __restrict__ C,
                                                 const float* __restrict__ P,
                                                 const float* __restrict__ bias,
                                                 const float* __restrict__ gamma,
                                                 const float* __restrict__ beta) {
  const int row = blockIdx.x;
  const int tid = threadIdx.x;
  float4 v = *reinterpret_cast<const float4*>(C + (size_t)row * OUT_F + tid * 4);
  const float4 p = *reinterpret_cast<const float4*>(P + (size_t)row * OUT_F + tid * 4);
  const float4 bb = *reinterpret_cast<const float4*>(bias + tid * 4);
  v.x += p.x + bb.x; v.y += p.y + bb.y; v.z += p.z + bb.z; v.w += p.w + bb.w;
  float s = v.x + v.y + v.z + v.w;
  float q = v.x * v.x + v.y * v.y + v.z * v.z + v.w * v.w;
#pragma unroll
  for (int off = 32; off > 0; off >>= 1) {
    s += __shfl_down(s, off);
    q += __shfl_down(q, off);
  }
  __shared__ float red[8];
  const int wave = tid >> 6, lane = tid & 63;
  if (lane == 0) { red[wave] = s; red[4 + wave] = q; }
  __syncthreads();
  s = red[0] + red[1] + red[2] + red[3];
  q = red[4] + red[5] + red[6] + red[7];
  const float mu = s * (1.0f / OUT_F);
  const float var = q * (1.0f / OUT_F) - mu * mu;
  const float rs = rsqrtf(var + LN_EPS);
  const float4 g = *reinterpret_cast<const float4*>(gamma + tid * 4);
  const float4 be = *reinterpret_cast<const float4*>(beta + tid * 4);
  float4 o;
  o.x = g.x * (v.x - mu) * rs + be.x;
  o.y = g.y * (v.y - mu) * rs + be.y;
  o.z = g.z * (v.z - mu) * rs + be.z;
  o.w = g.w * (v.w - mu) * rs + be.w;
  *reinterpret_cast<float4*>(C + (size_t)row * OUT_F + tid * 4) = o;
}

extern "C" void kernel_launch(void* const* d_in, const int* in_sizes, int n_in,
                              void* d_out, int out_size, void* d_ws, size_t ws_size,
                              hipStream_t stream) {
  const float* x     = (const float*)d_in[0];
  const float* cp    = (const float*)d_in[1];
  const float* W     = (const float*)d_in[2];
  const float* bias  = (const float*)d_in[3];
  const float* gamma = (const float*)d_in[4];
  const float* beta  = (const float*)d_in[5];
  float* out = (float*)d_out;

  unsigned short* Bm = (unsigned short*)d_ws;
  const size_t bBytes = (size_t)OUT_F * KP * sizeof(unsigned short);   // 24 MiB
  size_t avail = ws_size > bBytes ? ws_size - bBytes : 0;
  // per-row: 24 KiB bf16 features + 4 KiB fp32 partial
  const size_t perRow = (size_t)KP * 2 + (size_t)OUT_F * 4;
  long long fit = (long long)(avail / perRow);
  int chunk;
  if (fit >= BATCH)     chunk = BATCH;   // 512 WGs = 2 full fill rounds
  else if (fit >= 8192) chunk = 8192;    // 256 WGs = exact full fill
  else                  chunk = (int)((fit / 256) * 256);
  if (chunk < 256) chunk = 256;

  unsigned short* Af = (unsigned short*)((char*)d_ws + bBytes);
  float* P = (float*)(Af + (size_t)chunk * KP);

  bgen<<<OUT_F, 256, 0, stream>>>(cp, W, Bm);
  for (int r0 = 0; r0 < BATCH; r0 += chunk) {
    const int rows = (BATCH - r0 < chunk) ? (BATCH - r0) : chunk;
    featgen<<<rows, 256, 0, stream>>>(x, Af, r0);
    const int nbm = rows / 256;
    gemm8p<<<nbm * 8, 512, 0, stream>>>(Af, Bm, out + (size_t)r0 * OUT_F, P, nbm);
    ln_kernel<<<rows, 256, 0, stream>>>(out + (size_t)r0 * OUT_F, P, bias, gamma, beta);
  }
}

// Round 9
// 448.315 us; speedup vs baseline: 1.3440x; 1.0638x over previous
//
#include <hip/hip_runtime.h>
#include <hip/hip_bf16.h>

#define BATCH   16384
#define IN_F    1024
#define OUT_F   1024
#define KCOLS   11
#define KPL     12          // 11 basis planes + 1 x-plane (for W)
#define KP      (KPL*IN_F)  // 12288
#define KHALF   (KP/2)      // 6144 per split-K block
#define NTKH    (KHALF/64)  // 96 K-tiles of 64 per half
#define NITH    (NTKH/2)    // 48 main-loop iterations (2 K-tiles each)
#define LN_EPS  1e-5f

typedef __attribute__((ext_vector_type(8))) short short8;
typedef __attribute__((ext_vector_type(4))) float f32x4;

static __device__ __forceinline__ unsigned short f2bf(float f) {
  __hip_bfloat16 h = __float2bfloat16(f);
  return *reinterpret_cast<unsigned short*>(&h);
}

// Cox-de Boor, faithful to the reference's in-place variant.
// All denominators are compile-time constants -> multiply by folded reciprocal.
__device__ __forceinline__ void bspline_basis(float x, float bas[KCOLS]) {
  const float s = 1.0f / 11.0f;
  float kn[12];
#pragma unroll
  for (int j = 0; j < 12; ++j) kn[j] = (float)j * s;
  kn[11] = 1.0f;
#pragma unroll
  for (int j = 0; j < 11; ++j)
    bas[j] = (x >= kn[j] && x < kn[j + 1]) ? 1.0f : 0.0f;
#pragma unroll
  for (int d = 1; d <= 3; ++d) {
#pragma unroll
    for (int j = 0; j < 11 - d; ++j) {
      const float r1 = 1.0f / (kn[j + d] - kn[j]);
      const float r2 = 1.0f / (kn[j + d + 1] - kn[j + 1]);
      float a = (x - kn[j]) * r1;
      float c = (kn[j + d + 1] - x) * r2;
      bas[j] = a * bas[j] + c * bas[j + 1];
    }
  }
}

// A[localRow][k*1024 + i] (bf16): 11 basis planes + x plane.
__global__ __launch_bounds__(256) void featgen(const float* __restrict__ X,
                                               unsigned short* __restrict__ A,
                                               int row0) {
  const int brow = blockIdx.x;
  const int i0 = threadIdx.x * 4;
  const float4 xv = *reinterpret_cast<const float4*>(X + (size_t)(row0 + brow) * IN_F + i0);
  float xs[4] = {xv.x, xv.y, xv.z, xv.w};
  float bas[4][KCOLS];
#pragma unroll
  for (int t = 0; t < 4; ++t) bspline_basis(xs[t], bas[t]);
  unsigned short* outp = A + (size_t)brow * KP + i0;
#pragma unroll
  for (int k = 0; k < KCOLS; ++k) {
    ushort4 u;
    u.x = f2bf(bas[0][k]); u.y = f2bf(bas[1][k]);
    u.z = f2bf(bas[2][k]); u.w = f2bf(bas[3][k]);
    *reinterpret_cast<ushort4*>(outp + (size_t)k * IN_F) = u;
  }
  ushort4 u;
  u.x = f2bf(xs[0]); u.y = f2bf(xs[1]); u.z = f2bf(xs[2]); u.w = f2bf(xs[3]);
  *reinterpret_cast<ushort4*>(outp + (size_t)KCOLS * IN_F) = u;
}

// Bmat[o][k*1024 + i] (bf16): cp planes + W plane.
__global__ __launch_bounds__(256) void bgen(const float* __restrict__ CP,
                                            const float* __restrict__ W,
                                            unsigned short* __restrict__ Bm) {
  const int o = blockIdx.x;
  const int i0 = threadIdx.x * 4;
  unsigned short* outp = Bm + (size_t)o * KP + i0;
#pragma unroll
  for (int k = 0; k < KCOLS; ++k) {
    ushort4 u;
    u.x = f2bf(CP[((size_t)o * IN_F + i0 + 0) * KCOLS + k]);
    u.y = f2bf(CP[((size_t)o * IN_F + i0 + 1) * KCOLS + k]);
    u.z = f2bf(CP[((size_t)o * IN_F + i0 + 2) * KCOLS + k]);
    u.w = f2bf(CP[((size_t)o * IN_F + i0 + 3) * KCOLS + k]);
    *reinterpret_cast<ushort4*>(outp + (size_t)k * IN_F) = u;
  }
  ushort4 u;
  u.x = f2bf(W[(size_t)o * IN_F + i0 + 0]);
  u.y = f2bf(W[(size_t)o * IN_F + i0 + 1]);
  u.z = f2bf(W[(size_t)o * IN_F + i0 + 2]);
  u.w = f2bf(W[(size_t)o * IN_F + i0 + 3]);
  *reinterpret_cast<ushort4*>(outp + (size_t)KCOLS * IN_F) = u;
}

// ---- 256x256 split-K GEMM, 4 phases per 2 K-tiles (single trailing barrier) -
// ks=0 blocks -> Cc, ks=1 blocks -> Cp. Grid = nbm*8; 8192 rows -> 256 WGs.
// 512 thr = 8 waves (2M x 4N); BK=64; LDS 128 KiB double-buffered (A+B).
// Phase = one M-half x all N (32 MFMA). Counted waits: WAITV(4) at Ph2/Ph4
// drains the 8 older loads (prev B-stage + A-stage / B-stage + A-stage) just
// before the corresponding buffer is consumed; <=12 loads in flight.

#define BAR()    __builtin_amdgcn_s_barrier()
#define SCHED0() __builtin_amdgcn_sched_barrier(0)
#define WAITV(N) asm volatile("s_waitcnt vmcnt(" #N ")" ::: "memory")

__global__ __launch_bounds__(512, 2) void gemm8p(const unsigned short* __restrict__ A,
                                                 const unsigned short* __restrict__ Bm,
                                                 float* __restrict__ Cc,
                                                 float* __restrict__ Cp, int nbm) {
  __shared__ unsigned short lds[2][2][2][128 * 64];  // [buf][A=0/B=1][half][...]
  const int tid  = (int)threadIdx.x;
  const int lane = tid & 63;
  const int w    = tid >> 6;
  const int wm   = w >> 2;       // 0..1
  const int wn   = w & 3;        // 0..3

  // XCD-aware bijective swizzle; per-XCD chunk = {4 bm} x {2 ks} x {4 bn}.
  const int nwg = nbm * 8;
  const int cpx = nwg >> 3;
  const int bid = (int)blockIdx.x;
  const int swz = (bid & 7) * cpx + (bid >> 3);
  const int bn = swz & 3;
  const int ks = (swz >> 2) & 1;
  const int bm = swz >> 3;
  const size_t koff = (size_t)ks * KHALF;
  float* __restrict__ C = ks ? Cp : Cc;

  // staging: one issue = 512 thr x 16 B = 64 rows x 64 cols.
  // Linear LDS dest; source col carries the inverse swizzle c ^ (row&7).
  const int srow = (w << 3) + (lane >> 3);            // 0..63 within one issue
  const int scol = ((lane & 7) ^ (lane >> 3)) << 3;   // element col, swizzled
  const unsigned short* aB = A  + (size_t)(bm * 256 + srow) * KP + koff + scol;
  const unsigned short* bB = Bm + (size_t)(bn * 256 + srow) * KP + koff + scol;

#define STAGE(T, AB, H, BUF)                                                          \
  do {                                                                                \
    if ((T) < NTKH) {                                                                 \
      const unsigned short* g_ = ((AB) ? bB : aB) + (size_t)(H) * 128 * KP + (size_t)(T) * 64; \
      unsigned short* l_ = &lds[BUF][AB][H][w * 512];                                 \
      __builtin_amdgcn_global_load_lds((const __attribute__((address_space(1))) void*)g_,       \
                                       (__attribute__((address_space(3))) void*)l_, 16, 0, 0);  \
      __builtin_amdgcn_global_load_lds((const __attribute__((address_space(1))) void*)(g_ + (size_t)64 * KP), \
                                       (__attribute__((address_space(3))) void*)(l_ + 4096), 16, 0, 0); \
    }                                                                                 \
  } while (0)

  // fragment reads (ds_read_b128, swizzled col)
  const int fr = lane & 15;
  const int g4 = lane >> 4;
  const int s7 = lane & 7;
  const int col0 = ((g4 ^ s7) << 3);        // kk=0 (elements)
  const int col1 = (((4 + g4) ^ s7) << 3);  // kk=1
  const unsigned short* aH[2] = {&lds[0][0][wm][0], &lds[1][0][wm][0]};
  const unsigned short* bH[2] = {&lds[0][1][wn >> 1][0], &lds[1][1][wn >> 1][0]};
  const int brow0 = (wn & 1) * 64;

  short8 aF[4][2], bF[4][2];
  f32x4 acc[8][4] = {};

#define LOADA(MB, BUF)                                                         \
  do {                                                                         \
    _Pragma("unroll") for (int m_ = 0; m_ < 4; ++m_) {                         \
      const unsigned short* p_ = aH[BUF] + ((MB) + m_) * 1024 + fr * 64;       \
      aF[m_][0] = *reinterpret_cast<const short8*>(p_ + col0);                 \
      aF[m_][1] = *reinterpret_cast<const short8*>(p_ + col1);                 \
    }                                                                          \
  } while (0)

#define LOADB4(BUF)                                                            \
  do {                                                                         \
    _Pragma("unroll") for (int n_ = 0; n_ < 4; ++n_) {                         \
      const unsigned short* p_ = bH[BUF] + (brow0 + n_ * 16 + fr) * 64;        \
      bF[n_][0] = *reinterpret_cast<const short8*>(p_ + col0);                 \
      bF[n_][1] = *reinterpret_cast<const short8*>(p_ + col1);                 \
    }                                                                          \
  } while (0)

#define MFMAH(MB)                                                              \
  do {                                                                         \
    __builtin_amdgcn_s_setprio(1);                                             \
    _Pragma("unroll") for (int m_ = 0; m_ < 4; ++m_)                           \
    _Pragma("unroll") for (int n_ = 0; n_ < 4; ++n_)                           \
    _Pragma("unroll") for (int kk_ = 0; kk_ < 2; ++kk_)                        \
      acc[(MB) + m_][n_] = __builtin_amdgcn_mfma_f32_16x16x32_bf16(            \
          aF[m_][kk_], bF[n_][kk_], acc[(MB) + m_][n_], 0, 0, 0);              \
    __builtin_amdgcn_s_setprio(0);                                             \
  } while (0)

  // prologue: tile0 A+B -> buf0 (8 issues); tile1 B -> buf1 (4 issues);
  // wait buf0 complete (leave buf1-B's 4 in flight).
  STAGE(0, 0, 0, 0); STAGE(0, 0, 1, 0);
  STAGE(0, 1, 0, 0); STAGE(0, 1, 1, 0);
  STAGE(1, 1, 0, 1); STAGE(1, 1, 1, 1);
  WAITV(4);
  BAR();

#pragma unroll 1
  for (int j = 0; j < NITH; ++j) {
    const int tb = 2 * j + 1, t2 = 2 * j + 2, t3 = 2 * j + 3;
    // Ph1: tile a (buf0) m0-3 x n0-3; stage A(tb) -> buf1
    //      (buf1-A last read @prev Ph4, drained + barrier)
    LOADA(0, 0); LOADB4(0);
    STAGE(tb, 0, 0, 1); STAGE(tb, 0, 1, 1);
    MFMAH(0);
    SCHED0(); BAR();
    // Ph2: tile a m4-7 (bF regs persist); stage B(t2) -> buf0
    //      (B-buf0 reads @Ph1, drained + barrier); wait buf1 ready
    //      (drains prev-Ph4 B(tb) + Ph1 A(tb); leaves Ph2's own 4)
    LOADA(4, 0);
    STAGE(t2, 1, 0, 0); STAGE(t2, 1, 1, 0);
    MFMAH(4);
    if (j < NITH - 1) { WAITV(4); } else { WAITV(0); }
    SCHED0(); BAR();
    // Ph3: tile b (buf1) m0-3 x n0-3; stage A(t2) -> buf0
    //      (A-buf0 reads @Ph2, drained + barrier)
    LOADA(0, 1); LOADB4(1);
    STAGE(t2, 0, 0, 0); STAGE(t2, 0, 1, 0);
    MFMAH(0);
    SCHED0(); BAR();
    // Ph4: tile b m4-7; stage B(t3) -> buf1 (B-buf1 reads @Ph3, drained);
    //      wait buf0 (t2) ready (drains Ph2 B + Ph3 A; leaves Ph4's 4)
    LOADA(4, 1);
    STAGE(t3, 1, 0, 1); STAGE(t3, 1, 1, 1);
    MFMAH(4);
    if (j < NITH - 1) { WAITV(4); } else { WAITV(0); }
    SCHED0(); BAR();
  }

  // C/D layout (verified m89/m91): col = lane&15, row = (lane>>4)*4 + reg
  const size_t r0 = (size_t)bm * 256 + wm * 128 + (lane >> 4) * 4;
  const int c0 = bn * 256 + wn * 64 + fr;
#pragma unroll
  for (int m = 0; m < 8; ++m)
#pragma unroll
    for (int n = 0; n < 4; ++n)
#pragma unroll
      for (int r = 0; r < 4; ++r)
        C[(r0 + m * 16 + r) * OUT_F + (c0 + n * 16)] = acc[m][n][r];
}

// Row LayerNorm over C0+C1+bias, written in place to C0.
__global__ __launch_bounds__(256) void ln_kernel(float* __restrict__ C,
                                                 const float* __restrict__ P,
                                                 const float* __restrict__ bias,
                                                 const float* __restrict__ gamma,
                                                 const float* __restrict__ beta) {
  const int row = blockIdx.x;
  const int tid = threadIdx.x;
  float4 v = *reinterpret_cast<const float4*>(C + (size_t)row * OUT_F + tid * 4);
  const float4 p = *reinterpret_cast<const float4*>(P + (size_t)row * OUT_F + tid * 4);
  const float4 bb = *reinterpret_cast<const float4*>(bias + tid * 4);
  v.x += p.x + bb.x; v.y += p.y + bb.y; v.z += p.z + bb.z; v.w += p.w + bb.w;
  float s = v.x + v.y + v.z + v.w;
  float q = v.x * v.x + v.y * v.y + v.z * v.z + v.w * v.w;
#pragma unroll
  for (int off = 32; off > 0; off >>= 1) {
    s += __shfl_down(s, off);
    q += __shfl_down(q, off);
  }
  __shared__ float red[8];
  const int wave = tid >> 6, lane = tid & 63;
  if (lane == 0) { red[wave] = s; red[4 + wave] = q; }
  __syncthreads();
  s = red[0] + red[1] + red[2] + red[3];
  q = red[4] + red[5] + red[6] + red[7];
  const float mu = s * (1.0f / OUT_F);
  const float var = q * (1.0f / OUT_F) - mu * mu;
  const float rs = rsqrtf(var + LN_EPS);
  const float4 g = *reinterpret_cast<const float4*>(gamma + tid * 4);
  const float4 be = *reinterpret_cast<const float4*>(beta + tid * 4);
  float4 o;
  o.x = g.x * (v.x - mu) * rs + be.x;
  o.y = g.y * (v.y - mu) * rs + be.y;
  o.z = g.z * (v.z - mu) * rs + be.z;
  o.w = g.w * (v.w - mu) * rs + be.w;
  *reinterpret_cast<float4*>(C + (size_t)row * OUT_F + tid * 4) = o;
}

extern "C" void kernel_launch(void* const* d_in, const int* in_sizes, int n_in,
                              void* d_out, int out_size, void* d_ws, size_t ws_size,
                              hipStream_t stream) {
  const float* x     = (const float*)d_in[0];
  const float* cp    = (const float*)d_in[1];
  const float* W     = (const float*)d_in[2];
  const float* bias  = (const float*)d_in[3];
  const float* gamma = (const float*)d_in[4];
  const float* beta  = (const float*)d_in[5];
  float* out = (float*)d_out;

  unsigned short* Bm = (unsigned short*)d_ws;
  const size_t bBytes = (size_t)OUT_F * KP * sizeof(unsigned short);   // 24 MiB
  size_t avail = ws_size > bBytes ? ws_size - bBytes : 0;
  // per-row: 24 KiB bf16 features + 4 KiB fp32 partial
  const size_t perRow = (size_t)KP * 2 + (size_t)OUT_F * 4;
  long long fit = (long long)(avail / perRow);
  int chunk;
  if (fit >= BATCH)     chunk = BATCH;   // 512 WGs = 2 full fill rounds
  else if (fit >= 8192) chunk = 8192;    // 256 WGs = exact full fill
  else                  chunk = (int)((fit / 256) * 256);
  if (chunk < 256) chunk = 256;

  unsigned short* Af = (unsigned short*)((char*)d_ws + bBytes);
  float* P = (float*)(Af + (size_t)chunk * KP);

  bgen<<<OUT_F, 256, 0, stream>>>(cp, W, Bm);
  for (int r0 = 0; r0 < BATCH; r0 += chunk) {
    const int rows = (BATCH - r0 < chunk) ? (BATCH - r0) : chunk;
    featgen<<<rows, 256, 0, stream>>>(x, Af, r0);
    const int nbm = rows / 256;
    gemm8p<<<nbm * 8, 512, 0, stream>>>(Af, Bm, out + (size_t)r0 * OUT_F, P, nbm);
    ln_kernel<<<rows, 256, 0, stream>>>(out + (size_t)r0 * OUT_F, P, bias, gamma, beta);
  }
}